// Round 17
// baseline (1494.395 us; speedup 1.0000x reference)
//
#include <hip/hip_runtime.h>
#include <cstdint>

// ---------------- problem constants ----------------
constexpr int NP=50000, NT=200000, NA=20000, NG=500;
constexpr int NTOT = NP+NT+NA+NG;          // 270500
constexpr int RO_P=0, RO_T=NP, RO_A=NP+NT, RO_G=NP+NT+NA;
constexpr int E_TOT = 3720000;

constexpr int H_E [8] = {1000000,1000000,200000,200000,600000,600000,60000,60000};
constexpr int H_ES[9] = {0,1000000,2000000,2200000,2400000,3000000,3600000,3660000,3720000};
constexpr int H_NS[8] = {NP,NT,NT,NA,NT,NG,NA,NG};
constexpr int H_ND[8] = {NT,NP,NA,NT,NG,NT,NG,NA};
constexpr int H_SO[8] = {RO_P,RO_T,RO_T,RO_A,RO_T,RO_G,RO_A,RO_G};
constexpr int H_DO[8] = {RO_T,RO_P,RO_A,RO_T,RO_G,RO_T,RO_G,RO_A};
constexpr int H_RPO[8]= {0,200001,250002,270003,470004,470505,670506,671007};
constexpr int H_CO[8] = {0,200000,250000,270000,470000,470500,670500,671000};

__constant__ int c_E [8] = {1000000,1000000,200000,200000,600000,600000,60000,60000};
__constant__ int c_ES[9] = {0,1000000,2000000,2200000,2400000,3000000,3600000,3660000,3720000};
__constant__ int c_ND[8] = {200000,50000,20000,200000,500,200000,500,20000};
__constant__ int c_RPO[8]= {0,200001,250002,270003,470004,470505,670506,671007};
__constant__ int c_CO[8] = {0,200000,250000,270000,470000,470500,670500,671000};

__constant__ int sb_pref[9] = {0,196,245,265,461,462,658,659,679};
constexpr int SB_BLOCKS = 679;

constexpr int WSZ = 16384;   // window = 2^14
__constant__ int c_G [8] = {16,16,4,4,10,10,2,2};
__constant__ int c_CS[8] = {62500,62500,50000,50000,60000,60000,30000,30000};
__constant__ int c_NW[8] = {13,4,2,13,1,13,1,2};
__constant__ int gw_pref[9] = {0,208,272,280,332,342,472,474,478};
__constant__ int ch_pref[9] = {0,16,32,36,40,50,60,62,64};      // prefix of G
constexpr int GW_BLOCKS = 478;
constexpr int CH_BLOCKS = 64;
__constant__ int c_C2[8] = {0,3200000,4000000,4080000,4880000,4885000,6885000,6886000};
// cnt2 total = 6,926,000 ints (27.7 MB)

constexpr int OWT=0;
constexpr int OBT=448;
constexpr int OWPX=512;
constexpr int OBP=1024;
constexpr int OAV=1088;
constexpr int OBA=1152;
constexpr int OBG=1216;
constexpr int OBAGG=1280;
constexpr int OWAS=1792;
constexpr int OWAD=5888;
constexpr int OWG=9984;

struct EiPtrs { const int* p[8]; };

__device__ __forceinline__ unsigned short f2bf(float f){
  unsigned u = __float_as_uint(f);
  u += 0x7FFF + ((u>>16)&1);          // round-to-nearest-even
  return (unsigned short)(u>>16);
}
__device__ __forceinline__ float bf2f(unsigned short b){
  return __uint_as_float(((unsigned)b)<<16);
}

// ---------------- weight prep (grid-strided, 128 blocks) ----------------
__global__ __launch_bounds__(256) void k_prep(
  const float* __restrict__ pf_W, const float* __restrict__ pf_b,
  const float* __restrict__ tf_W, const float* __restrict__ tf_b,
  const float* __restrict__ af_W, const float* __restrict__ af_b,
  const float* __restrict__ gf_W, const float* __restrict__ gf_b,
  const float* __restrict__ ipWp, const float* __restrict__ ipbp,
  const float* __restrict__ ipWt, const float* __restrict__ ipbt,
  const float* __restrict__ ipWa, const float* __restrict__ ipba,
  const float* __restrict__ ipWg, const float* __restrict__ ipbg,
  const float* __restrict__ gatW, const float* __restrict__ gatB,
  const float* __restrict__ gatAs, const float* __restrict__ gatAd,
  float* __restrict__ cb)
{
  int tid = blockIdx.x*256 + threadIdx.x;
  int STR = gridDim.x*256;
  for(int i=tid;i<7*64;i+=STR){ int j=i>>6,c=i&63; float s=0.f;
    for(int k=0;k<64;k++) s += tf_W[j*64+k]*ipWt[k*64+c];
    cb[OWT+i]=s; }
  for(int i=tid;i<64;i+=STR){ float s=ipbt[i];
    for(int k=0;k<64;k++) s += tf_b[k]*ipWt[k*64+i];
    cb[OBT+i]=s; }
  for(int i=tid;i<8*64;i+=STR){ int j=i>>6,c=i&63; float s=0.f;
    for(int k=0;k<64;k++) s += pf_W[j*64+k]*ipWp[(64+k)*64+c];
    cb[OWPX+i]=s; }
  for(int i=tid;i<64;i+=STR){ float s=ipbp[i];
    for(int k=0;k<64;k++) s += pf_b[k]*ipWp[(64+k)*64+i];
    cb[OBP+i]=s; }
  for(int i=tid;i<64;i+=STR){ float s=0.f;
    for(int k=0;k<64;k++) s += af_W[k]*ipWa[(64+k)*64+i];
    cb[OAV+i]=s; }
  for(int i=tid;i<64;i+=STR){ float s=ipba[i];
    for(int k=0;k<64;k++) s += af_b[k]*ipWa[(64+k)*64+i];
    cb[OBA+i]=s; }
  for(int i=tid;i<64;i+=STR){ float s=ipbg[i];
    for(int k=0;k<64;k++) s += gf_b[k]*ipWg[k*64+i];
    cb[OBG+i]=s; }
  for(int i=tid;i<512;i+=STR){ int l=i>>8, t=(i>>6)&3, c=i&63;
    const float* B = gatB + l*8*64; float s;
    if(t==0)      s = B[1*64+c];
    else if(t==1) s = B[0*64+c]+B[3*64+c]+B[5*64+c];
    else if(t==2) s = B[2*64+c]+B[7*64+c];
    else          s = B[4*64+c]+B[6*64+c];
    cb[OBAGG+i]=s; }
  for(int i=tid;i<2*8*64*4;i+=STR){ int h=i&3, k=(i>>2)&63, lr=i>>8;
    const float* as = gatAs + lr*64;
    cb[OWAS+i] = ((k>>4)==h) ? as[h*16 + (k&15)] : 0.f;
    const float* W  = gatW + (size_t)lr*4096;
    const float* ad = gatAd + lr*64 + h*16;
    float d=0.f;
    for(int c=0;c<16;c++){ d += W[k*64+h*16+c]*ad[c]; }
    cb[OWAD+i]=d; }
  for(int i=tid;i<512*64;i+=STR){ int g=i>>6,c=i&63; float s=0.f;
    if(g<500){ for(int k=0;k<64;k++) s += gf_W[g*64+k]*ipWg[k*64+c]; }
    cb[OWG+i]=s; }
}

// ---------------- tiled [N,64]@[64,64] (+optional fused src attn-logits, bf16 out) ----------------
#define MM_DECL  __shared__ float sX[64*65]; __shared__ float sW[64*68]; \
  int tid=threadIdx.x; int rt=(tid>>4)<<2, ct=(tid&15)<<2; float acc[4][4];

#define MM_LOOP() \
  _Pragma("unroll 8") \
  for(int k=0;k<64;k++){ \
    float4 wv = *(const float4*)&sW[k*68+ct]; \
    float x0=sX[(rt+0)*65+k], x1=sX[(rt+1)*65+k], x2=sX[(rt+2)*65+k], x3=sX[(rt+3)*65+k]; \
    acc[0][0]+=x0*wv.x; acc[0][1]+=x0*wv.y; acc[0][2]+=x0*wv.z; acc[0][3]+=x0*wv.w; \
    acc[1][0]+=x1*wv.x; acc[1][1]+=x1*wv.y; acc[1][2]+=x1*wv.z; acc[1][3]+=x1*wv.w; \
    acc[2][0]+=x2*wv.x; acc[2][1]+=x2*wv.y; acc[2][2]+=x2*wv.z; acc[2][3]+=x2*wv.w; \
    acc[3][0]+=x3*wv.x; acc[3][1]+=x3*wv.y; acc[3][2]+=x3*wv.z; acc[3][3]+=x3*wv.w; \
  }

template<bool ALS, bool B16>
__global__ __launch_bounds__(256) void k_mm64(const float* __restrict__ X, const float* __restrict__ W,
  const float* __restrict__ bias, float* __restrict__ Y, float* __restrict__ alsY,
  const float* __restrict__ was, int N)
{
  MM_DECL
  int row0 = blockIdx.x*64;
  for(int i=tid;i<4096;i+=256){
    int r=i>>6, k=i&63;
    sX[r*65+k] = (row0+r<N)? X[(size_t)(row0+r)*64+k] : 0.f;
    sW[r*68+k] = W[i];
  }
  __syncthreads();
  #pragma unroll
  for(int i=0;i<4;i++){ acc[i][0]=0.f;acc[i][1]=0.f;acc[i][2]=0.f;acc[i][3]=0.f; }
  MM_LOOP()
  float4 bv = make_float4(0.f,0.f,0.f,0.f);
  if(bias) bv = *(const float4*)&bias[ct];
  #pragma unroll
  for(int i=0;i<4;i++){
    int row=row0+rt+i;
    if(row<N){
      if(B16){
        ushort4 o;
        o.x=f2bf(acc[i][0]+bv.x); o.y=f2bf(acc[i][1]+bv.y);
        o.z=f2bf(acc[i][2]+bv.z); o.w=f2bf(acc[i][3]+bv.w);
        *(ushort4*)&((unsigned short*)Y)[(size_t)row*64+ct] = o;
      } else {
        *(float4*)&Y[(size_t)row*64+ct] =
          make_float4(acc[i][0]+bv.x, acc[i][1]+bv.y, acc[i][2]+bv.z, acc[i][3]+bv.w);
      }
    }
  }
  if(ALS){
    float4 w0 = *(const float4*)&was[(ct+0)*4];
    float4 w1 = *(const float4*)&was[(ct+1)*4];
    float4 w2 = *(const float4*)&was[(ct+2)*4];
    float4 w3 = *(const float4*)&was[(ct+3)*4];
    #pragma unroll
    for(int i=0;i<4;i++){
      float4 p;
      p.x = acc[i][0]*w0.x + acc[i][1]*w1.x + acc[i][2]*w2.x + acc[i][3]*w3.x;
      p.y = acc[i][0]*w0.y + acc[i][1]*w1.y + acc[i][2]*w2.y + acc[i][3]*w3.y;
      p.z = acc[i][0]*w0.z + acc[i][1]*w1.z + acc[i][2]*w2.z + acc[i][3]*w3.z;
      p.w = acc[i][0]*w0.w + acc[i][1]*w1.w + acc[i][2]*w2.w + acc[i][3]*w3.w;
      #pragma unroll
      for(int m=1;m<16;m<<=1){
        p.x+=__shfl_xor(p.x,m); p.y+=__shfl_xor(p.y,m);
        p.z+=__shfl_xor(p.z,m); p.w+=__shfl_xor(p.w,m);
      }
      int row=row0+rt+i;
      if((tid&15)==0 && row<N) *(float4*)&alsY[(size_t)row*4] = p;
    }
  }
}

// ---------------- input projection (P/T/A) ----------------
constexpr int BP=(NP+63)/64, BT=(NT+63)/64, BA=(NA+63)/64;
__global__ __launch_bounds__(256) void k_init(
  const float* __restrict__ px, const float* __restrict__ tx, const float* __restrict__ ax,
  const float* __restrict__ embp, const float* __restrict__ emba,
  const int* __restrict__ pidx, const int* __restrict__ aidx,
  const float* __restrict__ ipWp, const float* __restrict__ ipWa,
  const float* __restrict__ cb, float* __restrict__ hout)
{
  MM_DECL
  __shared__ float sE[64*9];
  int bid = blockIdx.x;
  if(bid < BP){
    int row0 = bid*64;
    for(int i=tid;i<4096;i+=256){
      int r=i>>6,k=i&63; int row=row0+r;
      sX[r*65+k] = (row<NP)? embp[(size_t)pidx[row]*64+k] : 0.f;
      sW[r*68+k] = ipWp[i];
    }
    for(int i=tid;i<512;i+=256){ int r=i>>3,j=i&7; int row=row0+r;
      sE[r*9+j] = (row<NP)? px[(size_t)row*8+j] : 0.f; }
    __syncthreads();
    { float4 b = *(const float4*)&cb[OBP+ct];
      #pragma unroll
      for(int i=0;i<4;i++){ acc[i][0]=b.x;acc[i][1]=b.y;acc[i][2]=b.z;acc[i][3]=b.w; } }
    #pragma unroll
    for(int j=0;j<8;j++){
      float4 w = *(const float4*)&cb[OWPX + j*64 + ct];
      #pragma unroll
      for(int i=0;i<4;i++){ float xe = sE[(rt+i)*9+j];
        acc[i][0]+=xe*w.x; acc[i][1]+=xe*w.y; acc[i][2]+=xe*w.z; acc[i][3]+=xe*w.w; }
    }
    MM_LOOP()
    #pragma unroll
    for(int i=0;i<4;i++){ int row=row0+rt+i;
      if(row<NP) *(float4*)&hout[(size_t)(RO_P+row)*64+ct] =
        make_float4(acc[i][0],acc[i][1],acc[i][2],acc[i][3]); }
  } else if(bid < BP+BT){
    int row0 = (bid-BP)*64;
    for(int i=tid;i<512;i+=256){ int r=i>>3,j=i&7; int row=row0+r;
      sE[r*9+j] = (row<NT && j<7)? tx[(size_t)row*7+j] : 0.f; }
    __syncthreads();
    { float4 b = *(const float4*)&cb[OBT+ct];
      #pragma unroll
      for(int i=0;i<4;i++){ acc[i][0]=b.x;acc[i][1]=b.y;acc[i][2]=b.z;acc[i][3]=b.w; } }
    #pragma unroll
    for(int j=0;j<7;j++){
      float4 w = *(const float4*)&cb[OWT + j*64 + ct];
      #pragma unroll
      for(int i=0;i<4;i++){ float xe = sE[(rt+i)*9+j];
        acc[i][0]+=xe*w.x; acc[i][1]+=xe*w.y; acc[i][2]+=xe*w.z; acc[i][3]+=xe*w.w; }
    }
    #pragma unroll
    for(int i=0;i<4;i++){ int row=row0+rt+i;
      if(row<NT) *(float4*)&hout[(size_t)(RO_T+row)*64+ct] =
        make_float4(acc[i][0],acc[i][1],acc[i][2],acc[i][3]); }
  } else {
    int row0 = (bid-BP-BT)*64;
    for(int i=tid;i<4096;i+=256){
      int r=i>>6,k=i&63; int row=row0+r;
      sX[r*65+k] = (row<NA)? emba[(size_t)aidx[row]*64+k] : 0.f;
      sW[r*68+k] = ipWa[i];
    }
    for(int i=tid;i<64;i+=256){ int row=row0+i; sE[i] = (row<NA)? ax[row] : 0.f; }
    __syncthreads();
    #pragma unroll
    for(int i=0;i<4;i++){
      float4 b = *(const float4*)&cb[OBA+ct];
      float4 av = *(const float4*)&cb[OAV+ct];
      float xe = sE[rt+i];
      acc[i][0]=b.x+xe*av.x; acc[i][1]=b.y+xe*av.y; acc[i][2]=b.z+xe*av.z; acc[i][3]=b.w+xe*av.w;
    }
    MM_LOOP()
    #pragma unroll
    for(int i=0;i<4;i++){ int row=row0+rt+i;
      if(row<NA) *(float4*)&hout[(size_t)(RO_A+row)*64+ct] =
        make_float4(acc[i][0],acc[i][1],acc[i][2],acc[i][3]); }
  }
}

// genre init: 500 rows, K=500 (padded to 512)
__global__ __launch_bounds__(256) void k_init_g(const float* __restrict__ gx,
  const float* __restrict__ cb, float* __restrict__ hout)
{
  int wid = (blockIdx.x<<2)|(threadIdx.x>>6);
  int lane = threadIdx.x&63;
  if(wid>=NG) return;
  float acc = cb[OBG+lane];
  const float* WG = cb+OWG;
  for(int kb=0;kb<512;kb+=64){
    int k = kb+lane;
    float xv = (k<500)? gx[(size_t)wid*500+k] : 0.f;
    for(int j=0;j<64;j++){
      float x = __shfl(xv, j);
      acc += x * WG[(size_t)(kb+j)*64+lane];
    }
  }
  hout[(size_t)(RO_G+wid)*64+lane] = acc;
}

// ---------------- CSR build: window-partition first (no re-scan amplification) ----------------
// A: per-chunk bucket counts (per-wave LDS counters)
__global__ __launch_bounds__(1024) void k_bcnt(EiPtrs ei, int* __restrict__ bcnt){
  __shared__ int pcnt[16][16];
  int bid=blockIdx.x, tid=threadIdx.x;
  int r=0;
  #pragma unroll
  for(int q=1;q<8;q++) if(bid>=ch_pref[q]) r=q;
  int g = bid - ch_pref[r];
  if(tid<256) ((int*)pcnt)[tid]=0;
  __syncthreads();
  int wave = tid>>6;
  int E=c_E[r], CS=c_CS[r];
  int e0=g*CS, e1=min(e0+CS,E);
  const int* __restrict__ pd = ei.p[r]+E;
  for(int e=e0+tid;e<e1;e+=1024){
    int w = pd[e]>>14;
    atomicAdd(&pcnt[wave][w],1);
  }
  __syncthreads();
  if(tid<16 && tid<c_NW[r]){
    int s=0;
    #pragma unroll
    for(int wv=0;wv<16;wv++) s+=pcnt[wv][tid];
    bcnt[gw_pref[r] + g*c_NW[r] + tid] = s;
  }
}

// B: exclusive scan of 478 bucket counts (global across relations)
__global__ void k_bscan(const int* __restrict__ bcnt, int* __restrict__ bofs){
  if(threadIdx.x==0 && blockIdx.x==0){
    int run=0;
    for(int i=0;i<GW_BLOCKS;i++){ bofs[i]=run; run+=bcnt[i]; }
    bofs[GW_BLOCKS]=run;
  }
}

// C: partition edges into (r,g,w) buckets: esrc (int) + edl (u16 dst-local)
__global__ __launch_bounds__(1024) void k_part(EiPtrs ei, const int* __restrict__ bofs,
  int* __restrict__ esrc, unsigned short* __restrict__ edl){
  __shared__ int pofs[16];
  int bid=blockIdx.x, tid=threadIdx.x;
  int r=0;
  #pragma unroll
  for(int q=1;q<8;q++) if(bid>=ch_pref[q]) r=q;
  int g = bid - ch_pref[r];
  int NW=c_NW[r];
  if(tid<NW) pofs[tid] = bofs[gw_pref[r] + g*NW + tid];
  __syncthreads();
  int E=c_E[r], CS=c_CS[r];
  int e0=g*CS, e1=min(e0+CS,E);
  const int* __restrict__ ps = ei.p[r];
  const int* __restrict__ pd = ps+E;
  for(int e=e0+tid;e<e1;e+=1024){
    int dst = pd[e];
    int w = dst>>14;
    int pos = atomicAdd(&pofs[w],1);
    esrc[pos] = ps[e];
    edl[pos] = (unsigned short)(dst & 16383);
  }
}

// D: per-(g,w) dst histogram from its own bucket
__global__ __launch_bounds__(1024) void k_cntw(const int* __restrict__ bofs,
  const unsigned short* __restrict__ edl, int* __restrict__ cnt2){
  __shared__ int wcnt[WSZ];
  int bid=blockIdx.x, tid=threadIdx.x;
  int r=0;
  #pragma unroll
  for(int q=1;q<8;q++) if(bid>=gw_pref[q]) r=q;
  int local = bid - gw_pref[r];
  int NW=c_NW[r];
  int g = local/NW, w = local-g*NW;
  int lo=w*WSZ, nd=c_ND[r], n=min(WSZ,nd-lo);
  for(int i=tid;i<n;i+=1024) wcnt[i]=0;
  __syncthreads();
  int s0=bofs[bid], s1=bofs[bid+1];
  for(int j=s0+tid;j<s1;j+=1024) atomicAdd(&wcnt[edl[j]],1);
  __syncthreads();
  int* c = cnt2 + c_C2[r] + g*nd + lo;
  for(int i=tid;i<n;i+=1024) c[i]=wcnt[i];
}

// ---- segmented exclusive scan of cnt (= sum_g cnt2) -> rowptr (unchanged) ----
__global__ __launch_bounds__(1024) void k_scan1(const int* __restrict__ cnt2, int* __restrict__ bsum){
  int bid = blockIdx.x;
  int r=0;
  #pragma unroll
  for(int q=1;q<8;q++) if(bid>=sb_pref[q]) r=q;
  int lb = bid - sb_pref[r];
  int nd = c_ND[r];
  int idx = lb*1024 + threadIdx.x;
  int v = 0;
  if(idx<nd){
    int G=c_G[r]; int base=c_C2[r]+idx;
    for(int g=0;g<G;g++) v += cnt2[base+g*nd];
  }
  #pragma unroll
  for(int m=1;m<64;m<<=1) v += __shfl_xor(v,m);
  __shared__ int wsum[16];
  int lane = threadIdx.x&63, wid=threadIdx.x>>6;
  if(lane==0) wsum[wid]=v;
  __syncthreads();
  if(threadIdx.x==0){
    int s=0;
    #pragma unroll
    for(int w=0;w<16;w++) s+=wsum[w];
    bsum[bid]=s;
  }
}

__global__ __launch_bounds__(256) void k_scan2(int* __restrict__ bsum, int* __restrict__ rowptr){
  int r = blockIdx.x;
  int nb = sb_pref[r+1]-sb_pref[r];
  __shared__ int s[200];
  int tid=threadIdx.x;
  if(tid<nb) s[tid]=bsum[sb_pref[r]+tid];
  __syncthreads();
  if(tid==0){
    int run=0;
    for(int i=0;i<nb;i++){ int t=s[i]; s[i]=run; run+=t; }
    rowptr[c_RPO[r]+c_ND[r]] = run;
  }
  __syncthreads();
  if(tid<nb) bsum[sb_pref[r]+tid]=s[tid];
}

__global__ __launch_bounds__(1024) void k_scan3(const int* __restrict__ cnt2, const int* __restrict__ bsum,
  int* __restrict__ rowptr){
  int bid = blockIdx.x;
  int r=0;
  #pragma unroll
  for(int q=1;q<8;q++) if(bid>=sb_pref[q]) r=q;
  int lb = bid - sb_pref[r];
  int nd = c_ND[r];
  int tid = threadIdx.x;
  int idx = lb*1024 + tid;
  int v = 0;
  if(idx<nd){
    int G=c_G[r]; int base=c_C2[r]+idx;
    for(int g=0;g<G;g++) v += cnt2[base+g*nd];
  }
  __shared__ int s[1024];
  s[tid]=v;
  __syncthreads();
  #pragma unroll
  for(int off=1;off<1024;off<<=1){
    int t = (tid>=off)? s[tid-off] : 0;
    __syncthreads();
    s[tid]+=t;
    __syncthreads();
  }
  int ex = s[tid]-v + bsum[bid];
  if(idx<nd) rowptr[c_RPO[r]+idx]=ex;
}

__global__ __launch_bounds__(1024) void k_off2(const int* __restrict__ rowptr, int* __restrict__ cnt2){
  int bid = blockIdx.x;
  int r=0;
  #pragma unroll
  for(int q=1;q<8;q++) if(bid>=sb_pref[q]) r=q;
  int idx = (bid-sb_pref[r])*1024 + threadIdx.x;
  int nd = c_ND[r];
  if(idx<nd){
    int run = rowptr[c_RPO[r]+idx];
    int G=c_G[r]; int base=c_C2[r]+idx;
    for(int g=0;g<G;g++){
      int t = cnt2[base+g*nd];
      cnt2[base+g*nd] = run;
      run += t;
    }
  }
}

// F: scatter from bucket (contiguous read) into col
__global__ __launch_bounds__(1024) void k_scatw(const int* __restrict__ bofs,
  const int* __restrict__ esrc, const unsigned short* __restrict__ edl,
  const int* __restrict__ off2, int* __restrict__ col){
  __shared__ int wcur[WSZ];
  int bid=blockIdx.x, tid=threadIdx.x;
  int r=0;
  #pragma unroll
  for(int q=1;q<8;q++) if(bid>=gw_pref[q]) r=q;
  int local = bid - gw_pref[r];
  int NW=c_NW[r];
  int g = local/NW, w = local-g*NW;
  int lo=w*WSZ, nd=c_ND[r], n=min(WSZ,nd-lo);
  const int* o = off2 + c_C2[r] + g*nd + lo;
  for(int i=tid;i<n;i+=1024) wcur[i]=o[i];
  __syncthreads();
  int s0=bofs[bid], s1=bofs[bid+1];
  int* cl = col + c_ES[r];
  for(int j=s0+tid;j<s1;j+=1024){
    int pos = atomicAdd(&wcur[edl[j]],1);
    cl[pos] = esrc[j];
  }
}

// ---------------- per-dst aggregation (inline ald, 4x unroll, bf16 hs, optional fused epilogue) ----------------
template<bool FIRST, bool LAST>
__global__ __launch_bounds__(256) void k_agg(const int* __restrict__ rp, const int* __restrict__ col,
  const unsigned short* __restrict__ hs, const float* __restrict__ als,
  const float* __restrict__ Xd, const float* __restrict__ wad,
  float* __restrict__ out, int nd,
  const float* __restrict__ bagg, const float* __restrict__ lnw,
  const float* __restrict__ lnb, int resid)
{
  int wid = (blockIdx.x<<2)|(threadIdx.x>>6);
  int lane = threadIdx.x&63;
  if(wid>=nd) return;
  float x = Xd[(size_t)wid*64+lane];
  float4 wv = *(const float4*)&wad[lane*4];
  float a0=x*wv.x, a1=x*wv.y, a2=x*wv.z, a3=x*wv.w;
  #pragma unroll
  for(int m=1;m<64;m<<=1){
    a0+=__shfl_xor(a0,m); a1+=__shfl_xor(a1,m); a2+=__shfl_xor(a2,m); a3+=__shfl_xor(a3,m);
  }
  int h = lane>>4;
  float adv = (h==0)?a0:(h==1)?a1:(h==2)?a2:a3;
  int start = rp[wid], end = rp[wid+1];
  float den=0.f, acc=0.f;
  int j = start;
  for(; j+4<=end; j+=4){
    int s0=col[j], s1=col[j+1], s2=col[j+2], s3=col[j+3];
    float A0=als[(size_t)s0*4+h], A1=als[(size_t)s1*4+h];
    float A2=als[(size_t)s2*4+h], A3=als[(size_t)s3*4+h];
    float h0=bf2f(hs[(size_t)s0*64+lane]), h1=bf2f(hs[(size_t)s1*64+lane]);
    float h2=bf2f(hs[(size_t)s2*64+lane]), h3=bf2f(hs[(size_t)s3*64+lane]);
    float v0=A0+adv; v0=fmaxf(v0,0.2f*v0); float e0=__expf(v0);
    float v1=A1+adv; v1=fmaxf(v1,0.2f*v1); float e1=__expf(v1);
    float v2=A2+adv; v2=fmaxf(v2,0.2f*v2); float e2=__expf(v2);
    float v3=A3+adv; v3=fmaxf(v3,0.2f*v3); float e3=__expf(v3);
    den+=e0; acc+=e0*h0;
    den+=e1; acc+=e1*h1;
    den+=e2; acc+=e2*h2;
    den+=e3; acc+=e3*h3;
  }
  for(; j<end; j++){
    int s = col[j];
    float ah = als[(size_t)s*4+h] + adv;
    ah = fmaxf(ah, 0.2f*ah);
    float e = __expf(ah);
    den += e;
    acc += e*bf2f(hs[(size_t)s*64+lane]);
  }
  float r = acc/(den+1e-16f);
  size_t idx = (size_t)wid*64+lane;
  if(!LAST){
    if(FIRST) out[idx] = r;
    else      out[idx] += r;
  } else {
    float v = FIRST ? r : (out[idx] + r);
    v += bagg[lane];
    v = fmaxf(v, 0.f);
    if(resid) v += x;
    float s = v;
    #pragma unroll
    for(int m=1;m<64;m<<=1) s += __shfl_xor(s,m);
    float mu = s*(1.f/64.f);
    float d = v-mu;
    float q = d*d;
    #pragma unroll
    for(int m=1;m<64;m<<=1) q += __shfl_xor(q,m);
    float var = q*(1.f/64.f);
    out[idx] = d*rsqrtf(var+1e-5f)*lnw[lane] + lnb[lane];
  }
}

// ---------------- block-per-dst aggregation (tiny-nd relations: genre dst) ----------------
template<bool FIRST, bool LAST>
__global__ __launch_bounds__(1024) void k_agg_blk(const int* __restrict__ rp, const int* __restrict__ col,
  const unsigned short* __restrict__ hs, const float* __restrict__ als,
  const float* __restrict__ Xd, const float* __restrict__ wad,
  float* __restrict__ out, int nd,
  const float* __restrict__ bagg, const float* __restrict__ lnw,
  const float* __restrict__ lnb, int resid)
{
  int d = blockIdx.x;
  if(d>=nd) return;
  int tid=threadIdx.x, lane=tid&63, wid=tid>>6;
  __shared__ float sden[16*4];
  __shared__ float sacc[16][64];
  float x = Xd[(size_t)d*64+lane];
  float4 wv = *(const float4*)&wad[lane*4];
  float a0=x*wv.x, a1=x*wv.y, a2=x*wv.z, a3=x*wv.w;
  #pragma unroll
  for(int m=1;m<64;m<<=1){
    a0+=__shfl_xor(a0,m); a1+=__shfl_xor(a1,m); a2+=__shfl_xor(a2,m); a3+=__shfl_xor(a3,m);
  }
  int h = lane>>4;
  float adv = (h==0)?a0:(h==1)?a1:(h==2)?a2:a3;
  int start = rp[d], end = rp[d+1];
  float den=0.f, acc=0.f;
  int j = start+wid;
  for(; j+48<end; j+=64){
    int s0=col[j], s1=col[j+16], s2=col[j+32], s3=col[j+48];
    float A0=als[(size_t)s0*4+h], A1=als[(size_t)s1*4+h];
    float A2=als[(size_t)s2*4+h], A3=als[(size_t)s3*4+h];
    float h0=bf2f(hs[(size_t)s0*64+lane]), h1=bf2f(hs[(size_t)s1*64+lane]);
    float h2=bf2f(hs[(size_t)s2*64+lane]), h3=bf2f(hs[(size_t)s3*64+lane]);
    float v0=A0+adv; v0=fmaxf(v0,0.2f*v0); float e0=__expf(v0);
    float v1=A1+adv; v1=fmaxf(v1,0.2f*v1); float e1=__expf(v1);
    float v2=A2+adv; v2=fmaxf(v2,0.2f*v2); float e2=__expf(v2);
    float v3=A3+adv; v3=fmaxf(v3,0.2f*v3); float e3=__expf(v3);
    den+=e0; acc+=e0*h0;
    den+=e1; acc+=e1*h1;
    den+=e2; acc+=e2*h2;
    den+=e3; acc+=e3*h3;
  }
  for(; j<end; j+=16){
    int s = col[j];
    float ah = als[(size_t)s*4+h] + adv;
    ah = fmaxf(ah, 0.2f*ah);
    float e = __expf(ah);
    den += e;
    acc += e*bf2f(hs[(size_t)s*64+lane]);
  }
  if((lane&15)==0) sden[wid*4+h]=den;
  sacc[wid][lane]=acc;
  __syncthreads();
  if(tid<64){
    float s=0.f, dt=0.f;
    #pragma unroll
    for(int w=0;w<16;w++){ s+=sacc[w][tid]; dt+=sden[w*4+(tid>>4)]; }
    float r = s/(dt+1e-16f);
    size_t idx = (size_t)d*64+tid;
    if(!LAST){
      if(FIRST) out[idx] = r;
      else      out[idx] += r;
    } else {
      float v = FIRST ? r : (out[idx] + r);
      v += bagg[tid];
      v = fmaxf(v, 0.f);
      if(resid) v += x;               // tid<64 => lane==tid
      float sv = v;
      #pragma unroll
      for(int m=1;m<64;m<<=1) sv += __shfl_xor(sv,m);
      float mu = sv*(1.f/64.f);
      float dd = v-mu;
      float q = dd*dd;
      #pragma unroll
      for(int m=1;m<64;m<<=1) q += __shfl_xor(q,m);
      float var = q*(1.f/64.f);
      out[idx] = dd*rsqrtf(var+1e-5f)*lnw[tid] + lnb[tid];
    }
  }
}

// ---------------- host ----------------
extern "C" void kernel_launch(void* const* d_in, const int* in_sizes, int n_in,
                              void* d_out, int out_size, void* d_ws, size_t ws_size,
                              hipStream_t stream)
{
  const float* playlist_x=(const float*)d_in[0];
  const float* track_x   =(const float*)d_in[1];
  const float* artist_x  =(const float*)d_in[2];
  const float* genre_x   =(const float*)d_in[3];
  const float* embp=(const float*)d_in[4];
  const float* emba=(const float*)d_in[5];
  const float* pf_W=(const float*)d_in[6];  const float* pf_b=(const float*)d_in[7];
  const float* tf_W=(const float*)d_in[8];  const float* tf_b=(const float*)d_in[9];
  const float* af_W=(const float*)d_in[10]; const float* af_b=(const float*)d_in[11];
  const float* gf_W=(const float*)d_in[12]; const float* gf_b=(const float*)d_in[13];
  const float* ipWp=(const float*)d_in[14]; const float* ipbp=(const float*)d_in[15];
  const float* ipWt=(const float*)d_in[16]; const float* ipbt=(const float*)d_in[17];
  const float* ipWa=(const float*)d_in[18]; const float* ipba=(const float*)d_in[19];
  const float* ipWg=(const float*)d_in[20]; const float* ipbg=(const float*)d_in[21];
  const float* gatW=(const float*)d_in[22]; const float* gatB=(const float*)d_in[23];
  const float* gatAs=(const float*)d_in[24];const float* gatAd=(const float*)d_in[25];
  const float* lnw=(const float*)d_in[26];  const float* lnb=(const float*)d_in[27];
  const float* opWp=(const float*)d_in[28]; const float* opbp=(const float*)d_in[29];
  const float* opWt=(const float*)d_in[30]; const float* opbt=(const float*)d_in[31];
  const float* opWa=(const float*)d_in[32]; const float* opba=(const float*)d_in[33];
  const float* opWg=(const float*)d_in[34]; const float* opbg=(const float*)d_in[35];
  const int* pidx=(const int*)d_in[36];
  const int* aidx=(const int*)d_in[37];
  EiPtrs ei;
  for(int r=0;r<8;r++) ei.p[r]=(const int*)d_in[38+r];

  char* ws=(char*)d_ws;
  float* hA=(float*)d_out;
  float* cb = (float*)ws;

  size_t o_hB  = 256*1024;
  size_t o_hs  = o_hB + (size_t)NTOT*64*4;
  unsigned short* hs16 = (unsigned short*)(ws+o_hs);        // [200000,64] bf16 (25.6 MB)
  size_t o_als = o_hs + (size_t)NT*64*2;
  float* als=(float*)(ws+o_als);                            // [200000,4] (3.2 MB)
  size_t o_rp  = o_als + (size_t)NT*4*4;
  int* rowptr=(int*)(ws+o_rp);
  size_t o_col = o_rp + 691008*4;
  int* col=(int*)(ws+o_col);
  size_t o_esrc= o_col + (size_t)E_TOT*4;
  int* esrc=(int*)(ws+o_esrc);
  size_t o_edl = o_esrc + (size_t)E_TOT*4;
  unsigned short* edl=(unsigned short*)(ws+o_edl);
  size_t o_bc  = o_edl + (size_t)E_TOT*2;
  int* bcnt=(int*)(ws+o_bc);
  int* bofs=bcnt+GW_BLOCKS;                                 // 479 ints
  // cnt2/bsum overlap hs16+als (dead during CSR build): 27.7 MB < 28.8 MB
  int* cnt2=(int*)(ws+o_hs);
  int* bsum=cnt2+6926000;
  float* hB = (float*)(ws+o_hB);

  k_prep<<<128,256,0,stream>>>(pf_W,pf_b,tf_W,tf_b,af_W,af_b,gf_W,gf_b,
      ipWp,ipbp,ipWt,ipbt,ipWa,ipba,ipWg,ipbg,gatW,gatB,gatAs,gatAd,cb);
  k_init<<<BP+BT+BA,256,0,stream>>>(playlist_x,track_x,artist_x,embp,emba,pidx,aidx,ipWp,ipWa,cb,hA);
  k_init_g<<<(NG+3)/4,256,0,stream>>>(genre_x,cb,hA);

  k_bcnt<<<CH_BLOCKS,1024,0,stream>>>(ei,bcnt);
  k_bscan<<<1,64,0,stream>>>(bcnt,bofs);
  k_part<<<CH_BLOCKS,1024,0,stream>>>(ei,bofs,esrc,edl);
  k_cntw<<<GW_BLOCKS,1024,0,stream>>>(bofs,edl,cnt2);
  k_scan1<<<SB_BLOCKS,1024,0,stream>>>(cnt2,bsum);
  k_scan2<<<8,256,0,stream>>>(bsum,rowptr);
  k_scan3<<<SB_BLOCKS,1024,0,stream>>>(cnt2,bsum,rowptr);
  k_off2<<<SB_BLOCKS,1024,0,stream>>>(rowptr,cnt2);
  k_scatw<<<GW_BLOCKS,1024,0,stream>>>(bofs,esrc,edl,cnt2,col);

  for(int l=0;l<2;l++){
    float* hcur = l? hB : hA;
    float* hnew = l? hA : hB;
    const float* lw = lnw + l*64;
    const float* lb = lnb + l*64;
    for(int r=0;r<8;r++){
      int Ns=H_NS[r], Nd=H_ND[r];
      const float* Xs = hcur + (size_t)H_SO[r]*64;
      const float* Xd = hcur + (size_t)H_DO[r]*64;
      const float* W  = gatW + (size_t)(l*8+r)*4096;
      const float* was = cb+OWAS+(size_t)(l*8+r)*256;
      const float* wad = cb+OWAD+(size_t)(l*8+r)*256;
      float* outp = hnew + (size_t)H_DO[r]*64;
      int t = (r==1)?0 : (r==0||r==3||r==5)?1 : (r==2||r==7)?2 : 3;
      const float* bagg = cb + OBAGG + l*256 + t*64;
      k_mm64<true,true><<<(Ns+63)/64,256,0,stream>>>(Xs,W,nullptr,(float*)hs16,als,was,Ns);
      if(r==4){
        k_agg_blk<true ,false><<<Nd,1024,0,stream>>>(rowptr+H_RPO[r], col+H_ES[r], hs16, als, Xd, wad, outp, Nd, bagg, lw, lb, l);
      } else if(r==6){
        k_agg_blk<false,true ><<<Nd,1024,0,stream>>>(rowptr+H_RPO[r], col+H_ES[r], hs16, als, Xd, wad, outp, Nd, bagg, lw, lb, l);
      } else if(r==0 || r==2){
        k_agg<true ,false><<<(Nd+3)/4,256,0,stream>>>(rowptr+H_RPO[r], col+H_ES[r], hs16, als, Xd, wad, outp, Nd, bagg, lw, lb, l);
      } else if(r==3){
        k_agg<false,false><<<(Nd+3)/4,256,0,stream>>>(rowptr+H_RPO[r], col+H_ES[r], hs16, als, Xd, wad, outp, Nd, bagg, lw, lb, l);
      } else if(r==1){
        k_agg<true ,true ><<<(Nd+3)/4,256,0,stream>>>(rowptr+H_RPO[r], col+H_ES[r], hs16, als, Xd, wad, outp, Nd, bagg, lw, lb, l);
      } else { // r==5, r==7
        k_agg<false,true ><<<(Nd+3)/4,256,0,stream>>>(rowptr+H_RPO[r], col+H_ES[r], hs16, als, Xd, wad, outp, Nd, bagg, lw, lb, l);
      }
    }
  }
  k_mm64<false,false><<<(NP+63)/64,256,0,stream>>>(hA+(size_t)RO_P*64, opWp, opbp, hA+(size_t)RO_P*64, nullptr, nullptr, NP);
  k_mm64<false,false><<<(NT+63)/64,256,0,stream>>>(hA+(size_t)RO_T*64, opWt, opbt, hA+(size_t)RO_T*64, nullptr, nullptr, NT);
  k_mm64<false,false><<<(NA+63)/64,256,0,stream>>>(hA+(size_t)RO_A*64, opWa, opba, hA+(size_t)RO_A*64, nullptr, nullptr, NA);
  k_mm64<false,false><<<(NG+63)/64,256,0,stream>>>(hA+(size_t)RO_G*64, opWg, opbg, hA+(size_t)RO_G*64, nullptr, nullptr, NG);
}

// Round 18
// 1368.284 us; speedup vs baseline: 1.0922x; 1.0922x over previous
//
#include <hip/hip_runtime.h>
#include <cstdint>

// ---------------- problem constants ----------------
constexpr int NP=50000, NT=200000, NA=20000, NG=500;
constexpr int NTOT = NP+NT+NA+NG;          // 270500
constexpr int RO_P=0, RO_T=NP, RO_A=NP+NT, RO_G=NP+NT+NA;
constexpr int E_TOT = 3720000;

constexpr int H_E [8] = {1000000,1000000,200000,200000,600000,600000,60000,60000};
constexpr int H_ES[9] = {0,1000000,2000000,2200000,2400000,3000000,3600000,3660000,3720000};
constexpr int H_NS[8] = {NP,NT,NT,NA,NT,NG,NA,NG};
constexpr int H_ND[8] = {NT,NP,NA,NT,NG,NT,NG,NA};
constexpr int H_SO[8] = {RO_P,RO_T,RO_T,RO_A,RO_T,RO_G,RO_A,RO_G};
constexpr int H_DO[8] = {RO_T,RO_P,RO_A,RO_T,RO_G,RO_T,RO_G,RO_A};
constexpr int H_RPO[8]= {0,200001,250002,270003,470004,470505,670506,671007};
constexpr int H_CO[8] = {0,200000,250000,270000,470000,470500,670500,671000};

__constant__ int c_E [8] = {1000000,1000000,200000,200000,600000,600000,60000,60000};
__constant__ int c_ES[9] = {0,1000000,2000000,2200000,2400000,3000000,3600000,3660000,3720000};
__constant__ int c_ND[8] = {200000,50000,20000,200000,500,200000,500,20000};
__constant__ int c_RPO[8]= {0,200001,250002,270003,470004,470505,670506,671007};
__constant__ int c_CO[8] = {0,200000,250000,270000,470000,470500,670500,671000};

__constant__ int sb_pref[9] = {0,196,245,265,461,462,658,659,679};
constexpr int SB_BLOCKS = 679;

constexpr int WSZ = 16384;
__constant__ int c_G [8] = {16,16,4,4,10,10,2,2};
__constant__ int c_CS[8] = {62500,62500,50000,50000,60000,60000,30000,30000};
__constant__ int c_NW[8] = {13,4,2,13,1,13,1,2};
__constant__ int gw_pref[9] = {0,208,272,280,332,342,472,474,478};
constexpr int GW_BLOCKS = 478;
__constant__ int c_C2[8] = {0,3200000,4000000,4080000,4880000,4885000,6885000,6886000};
// cnt2 total = 6,926,000 ints (27.7 MB)

constexpr int OWT=0;
constexpr int OBT=448;
constexpr int OWPX=512;
constexpr int OBP=1024;
constexpr int OAV=1088;
constexpr int OBA=1152;
constexpr int OBG=1216;
constexpr int OBAGG=1280;
constexpr int OWAS=1792;
constexpr int OWAD=5888;
constexpr int OWG=9984;

struct EiPtrs { const int* p[8]; };

__device__ __forceinline__ unsigned short f2bf(float f){
  unsigned u = __float_as_uint(f);
  u += 0x7FFF + ((u>>16)&1);          // round-to-nearest-even
  return (unsigned short)(u>>16);
}
__device__ __forceinline__ float bf2f(unsigned short b){
  return __uint_as_float(((unsigned)b)<<16);
}

// ---------------- weight prep (grid-strided, 128 blocks) ----------------
__global__ __launch_bounds__(256) void k_prep(
  const float* __restrict__ pf_W, const float* __restrict__ pf_b,
  const float* __restrict__ tf_W, const float* __restrict__ tf_b,
  const float* __restrict__ af_W, const float* __restrict__ af_b,
  const float* __restrict__ gf_W, const float* __restrict__ gf_b,
  const float* __restrict__ ipWp, const float* __restrict__ ipbp,
  const float* __restrict__ ipWt, const float* __restrict__ ipbt,
  const float* __restrict__ ipWa, const float* __restrict__ ipba,
  const float* __restrict__ ipWg, const float* __restrict__ ipbg,
  const float* __restrict__ gatW, const float* __restrict__ gatB,
  const float* __restrict__ gatAs, const float* __restrict__ gatAd,
  float* __restrict__ cb)
{
  int tid = blockIdx.x*256 + threadIdx.x;
  int STR = gridDim.x*256;
  for(int i=tid;i<7*64;i+=STR){ int j=i>>6,c=i&63; float s=0.f;
    for(int k=0;k<64;k++) s += tf_W[j*64+k]*ipWt[k*64+c];
    cb[OWT+i]=s; }
  for(int i=tid;i<64;i+=STR){ float s=ipbt[i];
    for(int k=0;k<64;k++) s += tf_b[k]*ipWt[k*64+i];
    cb[OBT+i]=s; }
  for(int i=tid;i<8*64;i+=STR){ int j=i>>6,c=i&63; float s=0.f;
    for(int k=0;k<64;k++) s += pf_W[j*64+k]*ipWp[(64+k)*64+c];
    cb[OWPX+i]=s; }
  for(int i=tid;i<64;i+=STR){ float s=ipbp[i];
    for(int k=0;k<64;k++) s += pf_b[k]*ipWp[(64+k)*64+i];
    cb[OBP+i]=s; }
  for(int i=tid;i<64;i+=STR){ float s=0.f;
    for(int k=0;k<64;k++) s += af_W[k]*ipWa[(64+k)*64+i];
    cb[OAV+i]=s; }
  for(int i=tid;i<64;i+=STR){ float s=ipba[i];
    for(int k=0;k<64;k++) s += af_b[k]*ipWa[(64+k)*64+i];
    cb[OBA+i]=s; }
  for(int i=tid;i<64;i+=STR){ float s=ipbg[i];
    for(int k=0;k<64;k++) s += gf_b[k]*ipWg[k*64+i];
    cb[OBG+i]=s; }
  for(int i=tid;i<512;i+=STR){ int l=i>>8, t=(i>>6)&3, c=i&63;
    const float* B = gatB + l*8*64; float s;
    if(t==0)      s = B[1*64+c];
    else if(t==1) s = B[0*64+c]+B[3*64+c]+B[5*64+c];
    else if(t==2) s = B[2*64+c]+B[7*64+c];
    else          s = B[4*64+c]+B[6*64+c];
    cb[OBAGG+i]=s; }
  for(int i=tid;i<2*8*64*4;i+=STR){ int h=i&3, k=(i>>2)&63, lr=i>>8;
    const float* as = gatAs + lr*64;
    cb[OWAS+i] = ((k>>4)==h) ? as[h*16 + (k&15)] : 0.f;
    const float* W  = gatW + (size_t)lr*4096;
    const float* ad = gatAd + lr*64 + h*16;
    float d=0.f;
    for(int c=0;c<16;c++){ d += W[k*64+h*16+c]*ad[c]; }
    cb[OWAD+i]=d; }
  for(int i=tid;i<512*64;i+=STR){ int g=i>>6,c=i&63; float s=0.f;
    if(g<500){ for(int k=0;k<64;k++) s += gf_W[g*64+k]*ipWg[k*64+c]; }
    cb[OWG+i]=s; }
}

// ---------------- tiled [N,64]@[64,64] (+optional fused src attn-logits, bf16 out) ----------------
#define MM_DECL  __shared__ float sX[64*65]; __shared__ float sW[64*68]; \
  int tid=threadIdx.x; int rt=(tid>>4)<<2, ct=(tid&15)<<2; float acc[4][4];

#define MM_LOOP() \
  _Pragma("unroll 8") \
  for(int k=0;k<64;k++){ \
    float4 wv = *(const float4*)&sW[k*68+ct]; \
    float x0=sX[(rt+0)*65+k], x1=sX[(rt+1)*65+k], x2=sX[(rt+2)*65+k], x3=sX[(rt+3)*65+k]; \
    acc[0][0]+=x0*wv.x; acc[0][1]+=x0*wv.y; acc[0][2]+=x0*wv.z; acc[0][3]+=x0*wv.w; \
    acc[1][0]+=x1*wv.x; acc[1][1]+=x1*wv.y; acc[1][2]+=x1*wv.z; acc[1][3]+=x1*wv.w; \
    acc[2][0]+=x2*wv.x; acc[2][1]+=x2*wv.y; acc[2][2]+=x2*wv.z; acc[2][3]+=x2*wv.w; \
    acc[3][0]+=x3*wv.x; acc[3][1]+=x3*wv.y; acc[3][2]+=x3*wv.z; acc[3][3]+=x3*wv.w; \
  }

template<bool ALS, bool B16>
__global__ __launch_bounds__(256) void k_mm64(const float* __restrict__ X, const float* __restrict__ W,
  const float* __restrict__ bias, float* __restrict__ Y, float* __restrict__ alsY,
  const float* __restrict__ was, int N)
{
  MM_DECL
  int row0 = blockIdx.x*64;
  for(int i=tid;i<4096;i+=256){
    int r=i>>6, k=i&63;
    sX[r*65+k] = (row0+r<N)? X[(size_t)(row0+r)*64+k] : 0.f;
    sW[r*68+k] = W[i];
  }
  __syncthreads();
  #pragma unroll
  for(int i=0;i<4;i++){ acc[i][0]=0.f;acc[i][1]=0.f;acc[i][2]=0.f;acc[i][3]=0.f; }
  MM_LOOP()
  float4 bv = make_float4(0.f,0.f,0.f,0.f);
  if(bias) bv = *(const float4*)&bias[ct];
  #pragma unroll
  for(int i=0;i<4;i++){
    int row=row0+rt+i;
    if(row<N){
      if(B16){
        ushort4 o;
        o.x=f2bf(acc[i][0]+bv.x); o.y=f2bf(acc[i][1]+bv.y);
        o.z=f2bf(acc[i][2]+bv.z); o.w=f2bf(acc[i][3]+bv.w);
        *(ushort4*)&((unsigned short*)Y)[(size_t)row*64+ct] = o;
      } else {
        *(float4*)&Y[(size_t)row*64+ct] =
          make_float4(acc[i][0]+bv.x, acc[i][1]+bv.y, acc[i][2]+bv.z, acc[i][3]+bv.w);
      }
    }
  }
  if(ALS){
    float4 w0 = *(const float4*)&was[(ct+0)*4];
    float4 w1 = *(const float4*)&was[(ct+1)*4];
    float4 w2 = *(const float4*)&was[(ct+2)*4];
    float4 w3 = *(const float4*)&was[(ct+3)*4];
    #pragma unroll
    for(int i=0;i<4;i++){
      float4 p;
      p.x = acc[i][0]*w0.x + acc[i][1]*w1.x + acc[i][2]*w2.x + acc[i][3]*w3.x;
      p.y = acc[i][0]*w0.y + acc[i][1]*w1.y + acc[i][2]*w2.y + acc[i][3]*w3.y;
      p.z = acc[i][0]*w0.z + acc[i][1]*w1.z + acc[i][2]*w2.z + acc[i][3]*w3.z;
      p.w = acc[i][0]*w0.w + acc[i][1]*w1.w + acc[i][2]*w2.w + acc[i][3]*w3.w;
      #pragma unroll
      for(int m=1;m<16;m<<=1){
        p.x+=__shfl_xor(p.x,m); p.y+=__shfl_xor(p.y,m);
        p.z+=__shfl_xor(p.z,m); p.w+=__shfl_xor(p.w,m);
      }
      int row=row0+rt+i;
      if((tid&15)==0 && row<N) *(float4*)&alsY[(size_t)row*4] = p;
    }
  }
}

// ---------------- input projection (P/T/A) ----------------
constexpr int BP=(NP+63)/64, BT=(NT+63)/64, BA=(NA+63)/64;
__global__ __launch_bounds__(256) void k_init(
  const float* __restrict__ px, const float* __restrict__ tx, const float* __restrict__ ax,
  const float* __restrict__ embp, const float* __restrict__ emba,
  const int* __restrict__ pidx, const int* __restrict__ aidx,
  const float* __restrict__ ipWp, const float* __restrict__ ipWa,
  const float* __restrict__ cb, float* __restrict__ hout)
{
  MM_DECL
  __shared__ float sE[64*9];
  int bid = blockIdx.x;
  if(bid < BP){
    int row0 = bid*64;
    for(int i=tid;i<4096;i+=256){
      int r=i>>6,k=i&63; int row=row0+r;
      sX[r*65+k] = (row<NP)? embp[(size_t)pidx[row]*64+k] : 0.f;
      sW[r*68+k] = ipWp[i];
    }
    for(int i=tid;i<512;i+=256){ int r=i>>3,j=i&7; int row=row0+r;
      sE[r*9+j] = (row<NP)? px[(size_t)row*8+j] : 0.f; }
    __syncthreads();
    { float4 b = *(const float4*)&cb[OBP+ct];
      #pragma unroll
      for(int i=0;i<4;i++){ acc[i][0]=b.x;acc[i][1]=b.y;acc[i][2]=b.z;acc[i][3]=b.w; } }
    #pragma unroll
    for(int j=0;j<8;j++){
      float4 w = *(const float4*)&cb[OWPX + j*64 + ct];
      #pragma unroll
      for(int i=0;i<4;i++){ float xe = sE[(rt+i)*9+j];
        acc[i][0]+=xe*w.x; acc[i][1]+=xe*w.y; acc[i][2]+=xe*w.z; acc[i][3]+=xe*w.w; }
    }
    MM_LOOP()
    #pragma unroll
    for(int i=0;i<4;i++){ int row=row0+rt+i;
      if(row<NP) *(float4*)&hout[(size_t)(RO_P+row)*64+ct] =
        make_float4(acc[i][0],acc[i][1],acc[i][2],acc[i][3]); }
  } else if(bid < BP+BT){
    int row0 = (bid-BP)*64;
    for(int i=tid;i<512;i+=256){ int r=i>>3,j=i&7; int row=row0+r;
      sE[r*9+j] = (row<NT && j<7)? tx[(size_t)row*7+j] : 0.f; }
    __syncthreads();
    { float4 b = *(const float4*)&cb[OBT+ct];
      #pragma unroll
      for(int i=0;i<4;i++){ acc[i][0]=b.x;acc[i][1]=b.y;acc[i][2]=b.z;acc[i][3]=b.w; } }
    #pragma unroll
    for(int j=0;j<7;j++){
      float4 w = *(const float4*)&cb[OWT + j*64 + ct];
      #pragma unroll
      for(int i=0;i<4;i++){ float xe = sE[(rt+i)*9+j];
        acc[i][0]+=xe*w.x; acc[i][1]+=xe*w.y; acc[i][2]+=xe*w.z; acc[i][3]+=xe*w.w; }
    }
    #pragma unroll
    for(int i=0;i<4;i++){ int row=row0+rt+i;
      if(row<NT) *(float4*)&hout[(size_t)(RO_T+row)*64+ct] =
        make_float4(acc[i][0],acc[i][1],acc[i][2],acc[i][3]); }
  } else {
    int row0 = (bid-BP-BT)*64;
    for(int i=tid;i<4096;i+=256){
      int r=i>>6,k=i&63; int row=row0+r;
      sX[r*65+k] = (row<NA)? emba[(size_t)aidx[row]*64+k] : 0.f;
      sW[r*68+k] = ipWa[i];
    }
    for(int i=tid;i<64;i+=256){ int row=row0+i; sE[i] = (row<NA)? ax[row] : 0.f; }
    __syncthreads();
    #pragma unroll
    for(int i=0;i<4;i++){
      float4 b = *(const float4*)&cb[OBA+ct];
      float4 av = *(const float4*)&cb[OAV+ct];
      float xe = sE[rt+i];
      acc[i][0]=b.x+xe*av.x; acc[i][1]=b.y+xe*av.y; acc[i][2]=b.z+xe*av.z; acc[i][3]=b.w+xe*av.w;
    }
    MM_LOOP()
    #pragma unroll
    for(int i=0;i<4;i++){ int row=row0+rt+i;
      if(row<NA) *(float4*)&hout[(size_t)(RO_A+row)*64+ct] =
        make_float4(acc[i][0],acc[i][1],acc[i][2],acc[i][3]); }
  }
}

// genre init: 500 rows, K=500 (padded to 512)
__global__ __launch_bounds__(256) void k_init_g(const float* __restrict__ gx,
  const float* __restrict__ cb, float* __restrict__ hout)
{
  int wid = (blockIdx.x<<2)|(threadIdx.x>>6);
  int lane = threadIdx.x&63;
  if(wid>=NG) return;
  float acc = cb[OBG+lane];
  const float* WG = cb+OWG;
  for(int kb=0;kb<512;kb+=64){
    int k = kb+lane;
    float xv = (k<500)? gx[(size_t)wid*500+k] : 0.f;
    for(int j=0;j<64;j++){
      float x = __shfl(xv, j);
      acc += x * WG[(size_t)(kb+j)*64+lane];
    }
  }
  hout[(size_t)(RO_G+wid)*64+lane] = acc;
}

// ---------------- CSR build: two-level (chunk x window), LDS-private, atomic-free ----------------
__global__ __launch_bounds__(1024) void k_cnt2(EiPtrs ei, int* __restrict__ cnt2){
  __shared__ int wcnt[WSZ];
  int bid=blockIdx.x, tid=threadIdx.x;
  int r=0;
  #pragma unroll
  for(int q=1;q<8;q++) if(bid>=gw_pref[q]) r=q;
  int local = bid - gw_pref[r];
  int NW=c_NW[r];
  int g = local/NW, w = local-g*NW;
  int lo=w*WSZ, nd=c_ND[r], n=min(WSZ,nd-lo);
  for(int i=tid;i<n;i+=1024) wcnt[i]=0;
  __syncthreads();
  int E=c_E[r], CS=c_CS[r];
  int e0=g*CS, e1=min(e0+CS,E);
  const int* __restrict__ pd = ei.p[r]+E;
  for(int e=e0+tid;e<e1;e+=1024){
    int d = pd[e]-lo;
    if((unsigned)d < (unsigned)n) atomicAdd(&wcnt[d],1);
  }
  __syncthreads();
  int* c = cnt2 + c_C2[r] + g*nd + lo;
  for(int i=tid;i<n;i+=1024) c[i]=wcnt[i];
}

__global__ __launch_bounds__(1024) void k_scan1(const int* __restrict__ cnt2, int* __restrict__ bsum){
  int bid = blockIdx.x;
  int r=0;
  #pragma unroll
  for(int q=1;q<8;q++) if(bid>=sb_pref[q]) r=q;
  int lb = bid - sb_pref[r];
  int nd = c_ND[r];
  int idx = lb*1024 + threadIdx.x;
  int v = 0;
  if(idx<nd){
    int G=c_G[r]; int base=c_C2[r]+idx;
    for(int g=0;g<G;g++) v += cnt2[base+g*nd];
  }
  #pragma unroll
  for(int m=1;m<64;m<<=1) v += __shfl_xor(v,m);
  __shared__ int wsum[16];
  int lane = threadIdx.x&63, wid=threadIdx.x>>6;
  if(lane==0) wsum[wid]=v;
  __syncthreads();
  if(threadIdx.x==0){
    int s=0;
    #pragma unroll
    for(int w=0;w<16;w++) s+=wsum[w];
    bsum[bid]=s;
  }
}

__global__ __launch_bounds__(256) void k_scan2(int* __restrict__ bsum, int* __restrict__ rowptr){
  int r = blockIdx.x;
  int nb = sb_pref[r+1]-sb_pref[r];
  __shared__ int s[200];
  int tid=threadIdx.x;
  if(tid<nb) s[tid]=bsum[sb_pref[r]+tid];
  __syncthreads();
  if(tid==0){
    int run=0;
    for(int i=0;i<nb;i++){ int t=s[i]; s[i]=run; run+=t; }
    rowptr[c_RPO[r]+c_ND[r]] = run;
  }
  __syncthreads();
  if(tid<nb) bsum[sb_pref[r]+tid]=s[tid];
}

__global__ __launch_bounds__(1024) void k_scan3(const int* __restrict__ cnt2, const int* __restrict__ bsum,
  int* __restrict__ rowptr){
  int bid = blockIdx.x;
  int r=0;
  #pragma unroll
  for(int q=1;q<8;q++) if(bid>=sb_pref[q]) r=q;
  int lb = bid - sb_pref[r];
  int nd = c_ND[r];
  int tid = threadIdx.x;
  int idx = lb*1024 + tid;
  int v = 0;
  if(idx<nd){
    int G=c_G[r]; int base=c_C2[r]+idx;
    for(int g=0;g<G;g++) v += cnt2[base+g*nd];
  }
  __shared__ int s[1024];
  s[tid]=v;
  __syncthreads();
  #pragma unroll
  for(int off=1;off<1024;off<<=1){
    int t = (tid>=off)? s[tid-off] : 0;
    __syncthreads();
    s[tid]+=t;
    __syncthreads();
  }
  int ex = s[tid]-v + bsum[bid];
  if(idx<nd) rowptr[c_RPO[r]+idx]=ex;
}

__global__ __launch_bounds__(1024) void k_off2(const int* __restrict__ rowptr, int* __restrict__ cnt2){
  int bid = blockIdx.x;
  int r=0;
  #pragma unroll
  for(int q=1;q<8;q++) if(bid>=sb_pref[q]) r=q;
  int idx = (bid-sb_pref[r])*1024 + threadIdx.x;
  int nd = c_ND[r];
  if(idx<nd){
    int run = rowptr[c_RPO[r]+idx];
    int G=c_G[r]; int base=c_C2[r]+idx;
    for(int g=0;g<G;g++){
      int t = cnt2[base+g*nd];
      cnt2[base+g*nd] = run;
      run += t;
    }
  }
}

__global__ __launch_bounds__(1024) void k_scat2(EiPtrs ei, const int* __restrict__ off2,
  int* __restrict__ col){
  __shared__ int wcur[WSZ];
  int bid=blockIdx.x, tid=threadIdx.x;
  int r=0;
  #pragma unroll
  for(int q=1;q<8;q++) if(bid>=gw_pref[q]) r=q;
  int local = bid - gw_pref[r];
  int NW=c_NW[r];
  int g = local/NW, w = local-g*NW;
  int lo=w*WSZ, nd=c_ND[r], n=min(WSZ,nd-lo);
  const int* o = off2 + c_C2[r] + g*nd + lo;
  for(int i=tid;i<n;i+=1024) wcur[i]=o[i];
  __syncthreads();
  int E=c_E[r], CS=c_CS[r];
  int e0=g*CS, e1=min(e0+CS,E);
  const int* __restrict__ ps = ei.p[r];
  const int* __restrict__ pd = ps+E;
  int* cl = col + c_ES[r];
  for(int e=e0+tid;e<e1;e+=1024){
    int d = pd[e]-lo;
    if((unsigned)d < (unsigned)n){
      int pos = atomicAdd(&wcur[d],1);
      cl[pos] = ps[e];
    }
  }
}

// ---------------- per-dst aggregation (inline ald, 4x unroll, bf16 hs, optional fused epilogue) ----------------
template<bool FIRST, bool LAST>
__global__ __launch_bounds__(256) void k_agg(const int* __restrict__ rp, const int* __restrict__ col,
  const unsigned short* __restrict__ hs, const float* __restrict__ als,
  const float* __restrict__ Xd, const float* __restrict__ wad,
  float* __restrict__ out, int nd,
  const float* __restrict__ bagg, const float* __restrict__ lnw,
  const float* __restrict__ lnb, int resid)
{
  int wid = (blockIdx.x<<2)|(threadIdx.x>>6);
  int lane = threadIdx.x&63;
  if(wid>=nd) return;
  float x = Xd[(size_t)wid*64+lane];
  float4 wv = *(const float4*)&wad[lane*4];
  float a0=x*wv.x, a1=x*wv.y, a2=x*wv.z, a3=x*wv.w;
  #pragma unroll
  for(int m=1;m<64;m<<=1){
    a0+=__shfl_xor(a0,m); a1+=__shfl_xor(a1,m); a2+=__shfl_xor(a2,m); a3+=__shfl_xor(a3,m);
  }
  int h = lane>>4;
  float adv = (h==0)?a0:(h==1)?a1:(h==2)?a2:a3;
  int start = rp[wid], end = rp[wid+1];
  float den=0.f, acc=0.f;
  int j = start;
  for(; j+4<=end; j+=4){
    int s0=col[j], s1=col[j+1], s2=col[j+2], s3=col[j+3];
    float A0=als[(size_t)s0*4+h], A1=als[(size_t)s1*4+h];
    float A2=als[(size_t)s2*4+h], A3=als[(size_t)s3*4+h];
    float h0=bf2f(hs[(size_t)s0*64+lane]), h1=bf2f(hs[(size_t)s1*64+lane]);
    float h2=bf2f(hs[(size_t)s2*64+lane]), h3=bf2f(hs[(size_t)s3*64+lane]);
    float v0=A0+adv; v0=fmaxf(v0,0.2f*v0); float e0=__expf(v0);
    float v1=A1+adv; v1=fmaxf(v1,0.2f*v1); float e1=__expf(v1);
    float v2=A2+adv; v2=fmaxf(v2,0.2f*v2); float e2=__expf(v2);
    float v3=A3+adv; v3=fmaxf(v3,0.2f*v3); float e3=__expf(v3);
    den+=e0; acc+=e0*h0;
    den+=e1; acc+=e1*h1;
    den+=e2; acc+=e2*h2;
    den+=e3; acc+=e3*h3;
  }
  for(; j<end; j++){
    int s = col[j];
    float ah = als[(size_t)s*4+h] + adv;
    ah = fmaxf(ah, 0.2f*ah);
    float e = __expf(ah);
    den += e;
    acc += e*bf2f(hs[(size_t)s*64+lane]);
  }
  float r = acc/(den+1e-16f);
  size_t idx = (size_t)wid*64+lane;
  if(!LAST){
    if(FIRST) out[idx] = r;
    else      out[idx] += r;
  } else {
    float v = FIRST ? r : (out[idx] + r);
    v += bagg[lane];
    v = fmaxf(v, 0.f);
    if(resid) v += x;
    float s = v;
    #pragma unroll
    for(int m=1;m<64;m<<=1) s += __shfl_xor(s,m);
    float mu = s*(1.f/64.f);
    float d = v-mu;
    float q = d*d;
    #pragma unroll
    for(int m=1;m<64;m<<=1) q += __shfl_xor(q,m);
    float var = q*(1.f/64.f);
    out[idx] = d*rsqrtf(var+1e-5f)*lnw[lane] + lnb[lane];
  }
}

// ---------------- block-per-dst aggregation (tiny-nd relations: genre dst) ----------------
template<bool FIRST, bool LAST>
__global__ __launch_bounds__(1024) void k_agg_blk(const int* __restrict__ rp, const int* __restrict__ col,
  const unsigned short* __restrict__ hs, const float* __restrict__ als,
  const float* __restrict__ Xd, const float* __restrict__ wad,
  float* __restrict__ out, int nd,
  const float* __restrict__ bagg, const float* __restrict__ lnw,
  const float* __restrict__ lnb, int resid)
{
  int d = blockIdx.x;
  if(d>=nd) return;
  int tid=threadIdx.x, lane=tid&63, wid=tid>>6;
  __shared__ float sden[16*4];
  __shared__ float sacc[16][64];
  float x = Xd[(size_t)d*64+lane];
  float4 wv = *(const float4*)&wad[lane*4];
  float a0=x*wv.x, a1=x*wv.y, a2=x*wv.z, a3=x*wv.w;
  #pragma unroll
  for(int m=1;m<64;m<<=1){
    a0+=__shfl_xor(a0,m); a1+=__shfl_xor(a1,m); a2+=__shfl_xor(a2,m); a3+=__shfl_xor(a3,m);
  }
  int h = lane>>4;
  float adv = (h==0)?a0:(h==1)?a1:(h==2)?a2:a3;
  int start = rp[d], end = rp[d+1];
  float den=0.f, acc=0.f;
  int j = start+wid;
  for(; j+48<end; j+=64){
    int s0=col[j], s1=col[j+16], s2=col[j+32], s3=col[j+48];
    float A0=als[(size_t)s0*4+h], A1=als[(size_t)s1*4+h];
    float A2=als[(size_t)s2*4+h], A3=als[(size_t)s3*4+h];
    float h0=bf2f(hs[(size_t)s0*64+lane]), h1=bf2f(hs[(size_t)s1*64+lane]);
    float h2=bf2f(hs[(size_t)s2*64+lane]), h3=bf2f(hs[(size_t)s3*64+lane]);
    float v0=A0+adv; v0=fmaxf(v0,0.2f*v0); float e0=__expf(v0);
    float v1=A1+adv; v1=fmaxf(v1,0.2f*v1); float e1=__expf(v1);
    float v2=A2+adv; v2=fmaxf(v2,0.2f*v2); float e2=__expf(v2);
    float v3=A3+adv; v3=fmaxf(v3,0.2f*v3); float e3=__expf(v3);
    den+=e0; acc+=e0*h0;
    den+=e1; acc+=e1*h1;
    den+=e2; acc+=e2*h2;
    den+=e3; acc+=e3*h3;
  }
  for(; j<end; j+=16){
    int s = col[j];
    float ah = als[(size_t)s*4+h] + adv;
    ah = fmaxf(ah, 0.2f*ah);
    float e = __expf(ah);
    den += e;
    acc += e*bf2f(hs[(size_t)s*64+lane]);
  }
  if((lane&15)==0) sden[wid*4+h]=den;
  sacc[wid][lane]=acc;
  __syncthreads();
  if(tid<64){
    float s=0.f, dt=0.f;
    #pragma unroll
    for(int w=0;w<16;w++){ s+=sacc[w][tid]; dt+=sden[w*4+(tid>>4)]; }
    float r = s/(dt+1e-16f);
    size_t idx = (size_t)d*64+tid;
    if(!LAST){
      if(FIRST) out[idx] = r;
      else      out[idx] += r;
    } else {
      float v = FIRST ? r : (out[idx] + r);
      v += bagg[tid];
      v = fmaxf(v, 0.f);
      if(resid) v += x;               // tid<64 => lane==tid
      float sv = v;
      #pragma unroll
      for(int m=1;m<64;m<<=1) sv += __shfl_xor(sv,m);
      float mu = sv*(1.f/64.f);
      float dd = v-mu;
      float q = dd*dd;
      #pragma unroll
      for(int m=1;m<64;m<<=1) q += __shfl_xor(q,m);
      float var = q*(1.f/64.f);
      out[idx] = dd*rsqrtf(var+1e-5f)*lnw[tid] + lnb[tid];
    }
  }
}

// ---------------- host ----------------
extern "C" void kernel_launch(void* const* d_in, const int* in_sizes, int n_in,
                              void* d_out, int out_size, void* d_ws, size_t ws_size,
                              hipStream_t stream)
{
  const float* playlist_x=(const float*)d_in[0];
  const float* track_x   =(const float*)d_in[1];
  const float* artist_x  =(const float*)d_in[2];
  const float* genre_x   =(const float*)d_in[3];
  const float* embp=(const float*)d_in[4];
  const float* emba=(const float*)d_in[5];
  const float* pf_W=(const float*)d_in[6];  const float* pf_b=(const float*)d_in[7];
  const float* tf_W=(const float*)d_in[8];  const float* tf_b=(const float*)d_in[9];
  const float* af_W=(const float*)d_in[10]; const float* af_b=(const float*)d_in[11];
  const float* gf_W=(const float*)d_in[12]; const float* gf_b=(const float*)d_in[13];
  const float* ipWp=(const float*)d_in[14]; const float* ipbp=(const float*)d_in[15];
  const float* ipWt=(const float*)d_in[16]; const float* ipbt=(const float*)d_in[17];
  const float* ipWa=(const float*)d_in[18]; const float* ipba=(const float*)d_in[19];
  const float* ipWg=(const float*)d_in[20]; const float* ipbg=(const float*)d_in[21];
  const float* gatW=(const float*)d_in[22]; const float* gatB=(const float*)d_in[23];
  const float* gatAs=(const float*)d_in[24];const float* gatAd=(const float*)d_in[25];
  const float* lnw=(const float*)d_in[26];  const float* lnb=(const float*)d_in[27];
  const float* opWp=(const float*)d_in[28]; const float* opbp=(const float*)d_in[29];
  const float* opWt=(const float*)d_in[30]; const float* opbt=(const float*)d_in[31];
  const float* opWa=(const float*)d_in[32]; const float* opba=(const float*)d_in[33];
  const float* opWg=(const float*)d_in[34]; const float* opbg=(const float*)d_in[35];
  const int* pidx=(const int*)d_in[36];
  const int* aidx=(const int*)d_in[37];
  EiPtrs ei;
  for(int r=0;r<8;r++) ei.p[r]=(const int*)d_in[38+r];

  char* ws=(char*)d_ws;
  float* hA=(float*)d_out;
  float* cb = (float*)ws;

  size_t o_hB  = 256*1024;
  size_t o_hs  = o_hB + (size_t)NTOT*64*4;
  unsigned short* hs16 = (unsigned short*)(ws+o_hs);        // [200000,64] bf16 (25.6 MB)
  size_t o_als = o_hs + (size_t)NT*64*2;
  float* als=(float*)(ws+o_als);                            // [200000,4] (3.2 MB)
  size_t o_rp  = o_als + (size_t)NT*4*4;
  int* rowptr=(int*)(ws+o_rp);
  size_t o_col = o_rp + 691008*4;
  int* col=(int*)(ws+o_col);
  // cnt2/bsum overlap hs16+als (dead during CSR build): 27.7 MB < 28.8 MB
  int* cnt2=(int*)(ws+o_hs);
  int* bsum=cnt2+6926000;
  float* hB = (float*)(ws+o_hB);

  k_prep<<<128,256,0,stream>>>(pf_W,pf_b,tf_W,tf_b,af_W,af_b,gf_W,gf_b,
      ipWp,ipbp,ipWt,ipbt,ipWa,ipba,ipWg,ipbg,gatW,gatB,gatAs,gatAd,cb);
  k_init<<<BP+BT+BA,256,0,stream>>>(playlist_x,track_x,artist_x,embp,emba,pidx,aidx,ipWp,ipWa,cb,hA);
  k_init_g<<<(NG+3)/4,256,0,stream>>>(genre_x,cb,hA);

  k_cnt2<<<GW_BLOCKS,1024,0,stream>>>(ei,cnt2);
  k_scan1<<<SB_BLOCKS,1024,0,stream>>>(cnt2,bsum);
  k_scan2<<<8,256,0,stream>>>(bsum,rowptr);
  k_scan3<<<SB_BLOCKS,1024,0,stream>>>(cnt2,bsum,rowptr);
  k_off2<<<SB_BLOCKS,1024,0,stream>>>(rowptr,cnt2);
  k_scat2<<<GW_BLOCKS,1024,0,stream>>>(ei,cnt2,col);

  for(int l=0;l<2;l++){
    float* hcur = l? hB : hA;
    float* hnew = l? hA : hB;
    const float* lw = lnw + l*64;
    const float* lb = lnb + l*64;
    for(int r=0;r<8;r++){
      int Ns=H_NS[r], Nd=H_ND[r];
      const float* Xs = hcur + (size_t)H_SO[r]*64;
      const float* Xd = hcur + (size_t)H_DO[r]*64;
      const float* W  = gatW + (size_t)(l*8+r)*4096;
      const float* was = cb+OWAS+(size_t)(l*8+r)*256;
      const float* wad = cb+OWAD+(size_t)(l*8+r)*256;
      float* outp = hnew + (size_t)H_DO[r]*64;
      // dst type per relation: 1->P(0), 0/3/5->T(1), 2/7->A(2), 4/6->G(3)
      int t = (r==1)?0 : (r==0||r==3||r==5)?1 : (r==2||r==7)?2 : 3;
      const float* bagg = cb + OBAGG + l*256 + t*64;
      k_mm64<true,true><<<(Ns+63)/64,256,0,stream>>>(Xs,W,nullptr,(float*)hs16,als,was,Ns);
      if(r==4){
        k_agg_blk<true ,false><<<Nd,1024,0,stream>>>(rowptr+H_RPO[r], col+H_ES[r], hs16, als, Xd, wad, outp, Nd, bagg, lw, lb, l);
      } else if(r==6){
        k_agg_blk<false,true ><<<Nd,1024,0,stream>>>(rowptr+H_RPO[r], col+H_ES[r], hs16, als, Xd, wad, outp, Nd, bagg, lw, lb, l);
      } else if(r==0 || r==2){
        k_agg<true ,false><<<(Nd+3)/4,256,0,stream>>>(rowptr+H_RPO[r], col+H_ES[r], hs16, als, Xd, wad, outp, Nd, bagg, lw, lb, l);
      } else if(r==3){
        k_agg<false,false><<<(Nd+3)/4,256,0,stream>>>(rowptr+H_RPO[r], col+H_ES[r], hs16, als, Xd, wad, outp, Nd, bagg, lw, lb, l);
      } else if(r==1){
        k_agg<true ,true ><<<(Nd+3)/4,256,0,stream>>>(rowptr+H_RPO[r], col+H_ES[r], hs16, als, Xd, wad, outp, Nd, bagg, lw, lb, l);
      } else { // r==5, r==7
        k_agg<false,true ><<<(Nd+3)/4,256,0,stream>>>(rowptr+H_RPO[r], col+H_ES[r], hs16, als, Xd, wad, outp, Nd, bagg, lw, lb, l);
      }
    }
  }
  k_mm64<false,false><<<(NP+63)/64,256,0,stream>>>(hA+(size_t)RO_P*64, opWp, opbp, hA+(size_t)RO_P*64, nullptr, nullptr, NP);
  k_mm64<false,false><<<(NT+63)/64,256,0,stream>>>(hA+(size_t)RO_T*64, opWt, opbt, hA+(size_t)RO_T*64, nullptr, nullptr, NT);
  k_mm64<false,false><<<(NA+63)/64,256,0,stream>>>(hA+(size_t)RO_A*64, opWa, opba, hA+(size_t)RO_A*64, nullptr, nullptr, NA);
  k_mm64<false,false><<<(NG+63)/64,256,0,stream>>>(hA+(size_t)RO_G*64, opWg, opbg, hA+(size_t)RO_G*64, nullptr, nullptr, NG);
}